// Round 1
// baseline (4976.657 us; speedup 1.0000x reference)
//
#include <hip/hip_runtime.h>
#include <hip/hip_bf16.h>
#include <math.h>

#define N_NODES 20000
#define N_EDGES 320000
#define T_STEPS 16
#define F_INDIM 128
#define HC 256      // heads * channels for both GAT layers
#define HEADS 4
#define CDIM 64
#define G3 192      // 3 * F2 gru gate width

// ---------------- CSR build ----------------

__global__ void k_init_cnt(int* __restrict__ cnt) {
    int i = blockIdx.x * 256 + threadIdx.x;
    if (i < N_NODES) cnt[i] = 1;   // self-loop
}

__global__ void k_count(const int* __restrict__ ei, int* __restrict__ cnt) {
    int i = blockIdx.x * 256 + threadIdx.x;
    if (i < N_EDGES) atomicAdd(&cnt[ei[N_EDGES + i]], 1);
}

__global__ __launch_bounds__(1024) void k_scan(const int* __restrict__ cnt,
                                               int* __restrict__ off,
                                               int* __restrict__ cur) {
    __shared__ int sdata[1024];
    int tid = threadIdx.x;
    const int ITEMS = (N_NODES + 1023) / 1024;   // 20
    int start = tid * ITEMS;
    int local = 0;
    for (int i = 0; i < ITEMS; ++i) {
        int idx = start + i;
        if (idx < N_NODES) local += cnt[idx];
    }
    sdata[tid] = local;
    __syncthreads();
    for (int s = 1; s < 1024; s <<= 1) {
        int v = (tid >= s) ? sdata[tid - s] : 0;
        __syncthreads();
        sdata[tid] += v;
        __syncthreads();
    }
    int run = sdata[tid] - local;   // exclusive
    for (int i = 0; i < ITEMS; ++i) {
        int idx = start + i;
        if (idx < N_NODES) {
            off[idx] = run;
            cur[idx] = run;
            run += cnt[idx];
        }
    }
    if (tid == 0) off[N_NODES] = N_EDGES + N_NODES;
}

__global__ void k_fill(const int* __restrict__ ei, int* __restrict__ cur,
                       int* __restrict__ csr) {
    int i = blockIdx.x * 256 + threadIdx.x;
    if (i < N_EDGES) {
        int s = ei[i];
        int d = ei[N_EDGES + i];
        int pos = atomicAdd(&cur[d], 1);
        csr[pos] = s;
    } else if (i < N_EDGES + N_NODES) {
        int d = i - N_EDGES;
        int pos = atomicAdd(&cur[d], 1);
        csr[pos] = d;
    }
}

// ---------------- GEMM: C[nrows x M] = A[nrows x K] * B[K x M] ----------------
// 64x64 tile, 256 threads, 4x4 per thread, BK=16. M multiple of 64, K multiple of 16.

__global__ __launch_bounds__(256) void k_gemm(const float* __restrict__ A, int lda,
                                              const float* __restrict__ B, int ldb,
                                              float* __restrict__ C, int ldc,
                                              int nrows, int K) {
    __shared__ __align__(16) float As[16][72];   // [k][row], padded
    __shared__ __align__(16) float Bs[16][64];   // [k][col]
    int tid = threadIdx.x;
    int row0 = blockIdx.y * 64;
    int col0 = blockIdx.x * 64;
    int tx = tid & 15, ty = tid >> 4;
    float acc[4][4] = {};
    int kA = tid & 15, iA0 = tid >> 4;
    int cB = tid & 63, kB0 = tid >> 6;

    for (int kk = 0; kk < K; kk += 16) {
#pragma unroll
        for (int r = 0; r < 4; ++r) {
            int i = iA0 + 16 * r;
            int row = row0 + i;
            As[kA][i] = (row < nrows) ? A[(size_t)row * lda + kk + kA] : 0.f;
        }
#pragma unroll
        for (int r = 0; r < 4; ++r) {
            int k = kB0 + 4 * r;
            Bs[k][cB] = B[(size_t)(kk + k) * ldb + col0 + cB];
        }
        __syncthreads();
#pragma unroll
        for (int k = 0; k < 16; ++k) {
            float4 a4 = *(const float4*)&As[k][ty * 4];
            float4 b4 = *(const float4*)&Bs[k][tx * 4];
            float av[4] = {a4.x, a4.y, a4.z, a4.w};
            float bv[4] = {b4.x, b4.y, b4.z, b4.w};
#pragma unroll
            for (int i = 0; i < 4; ++i)
#pragma unroll
                for (int j = 0; j < 4; ++j)
                    acc[i][j] = fmaf(av[i], bv[j], acc[i][j]);
        }
        __syncthreads();
    }
#pragma unroll
    for (int i = 0; i < 4; ++i) {
        int row = row0 + ty * 4 + i;
        if (row < nrows) {
            float4 v = make_float4(acc[i][0], acc[i][1], acc[i][2], acc[i][3]);
            *(float4*)&C[(size_t)row * ldc + col0 + tx * 4] = v;
        }
    }
}

// ---------------- attention alpha prep: as[n,h] = <h[n,h,:], a_src[h,:]> ----------------

__global__ void k_attn_prep(const float* __restrict__ h, const float* __restrict__ a_src,
                            const float* __restrict__ a_dst,
                            float* __restrict__ asb, float* __restrict__ adb) {
    int idx = blockIdx.x * 256 + threadIdx.x;
    if (idx >= N_NODES * HEADS) return;
    int n = idx >> 2, hh = idx & 3;
    const float4* row = (const float4*)(h + (size_t)n * HC + hh * CDIM);
    const float4* av = (const float4*)(a_src + hh * CDIM);
    const float4* bv = (const float4*)(a_dst + hh * CDIM);
    float s1 = 0.f, s2 = 0.f;
#pragma unroll
    for (int c4 = 0; c4 < CDIM / 4; ++c4) {
        float4 v = row[c4], a = av[c4], b = bv[c4];
        s1 += v.x * a.x + v.y * a.y + v.z * a.z + v.w * a.w;
        s2 += v.x * b.x + v.y * b.y + v.z * b.z + v.w * b.w;
    }
    asb[idx] = s1;
    adb[idx] = s2;
}

// ---------------- GAT aggregation: one block per destination node ----------------
// 256 threads = 4 waves, wave w handles head w; lane = channel.

template <bool CONCAT>
__global__ __launch_bounds__(256) void k_gat_agg(const float* __restrict__ hfeat,
                                                 const float* __restrict__ asb,
                                                 const float* __restrict__ adb,
                                                 const int* __restrict__ off,
                                                 const int* __restrict__ csr,
                                                 const float* __restrict__ bias,
                                                 float* __restrict__ out) {
    __shared__ float s_max[HEADS];
    __shared__ int s_src[64];
    __shared__ float s_w[64][HEADS];
    __shared__ float s_acc[HEADS][CDIM];

    int d = blockIdx.x;
    int tid = threadIdx.x;
    int h = tid >> 6;       // wave id = head
    int c = tid & 63;       // lane = channel
    int beg = off[d];
    int deg = off[d + 1] - beg;

    // phase 1: per-head max of leaky_relu(as[src]+ad[d])
    float adh = adb[d * HEADS + h];
    float lmax = -1e30f;
    for (int j = c; j < deg; j += 64) {
        int s = csr[beg + j];
        float sc = asb[s * HEADS + h] + adh;
        sc = sc > 0.f ? sc : 0.2f * sc;
        lmax = fmaxf(lmax, sc);
    }
#pragma unroll
    for (int s = 32; s >= 1; s >>= 1)
        lmax = fmaxf(lmax, __shfl_xor(lmax, s, 64));
    if (c == 0) s_max[h] = lmax;
    __syncthreads();

    // per-thread constants for the chunked weight computation (role: j=tid>>2, hh=tid&3)
    int hhw = tid & 3;
    float mC = s_max[hhw];
    float adC = adb[d * HEADS + hhw];

    float acc = 0.f, denom = 0.f;
    for (int base = 0; base < deg; base += 64) {
        int len = min(64, deg - base);
        __syncthreads();   // previous chunk's accumulate done
        if (tid < 64) s_src[tid] = (tid < len) ? csr[beg + base + tid] : 0;
        __syncthreads();
        {
            int j = tid >> 2;
            float w = 0.f;
            if (j < len) {
                int s = s_src[j];
                float sc = asb[s * HEADS + hhw] + adC;
                sc = sc > 0.f ? sc : 0.2f * sc;
                w = expf(sc - mC);
            }
            s_w[j][hhw] = w;
        }
        __syncthreads();
        for (int j = 0; j < len; ++j) {
            float w = s_w[j][h];
            denom += w;
            acc = fmaf(w, hfeat[(size_t)s_src[j] * HC + h * CDIM + c], acc);
        }
    }
    float val = acc / (denom + 1e-16f);

    if (CONCAT) {
        float o = val + bias[h * CDIM + c];
        out[(size_t)d * HC + h * CDIM + c] = o > 0.f ? o : 0.f;
    } else {
        s_acc[h][c] = val;
        __syncthreads();
        if (tid < CDIM) {
            float m = (s_acc[0][tid] + s_acc[1][tid] + s_acc[2][tid] + s_acc[3][tid]) * 0.25f;
            float o = m + bias[tid];
            out[(size_t)d * CDIM + tid] = o > 0.f ? o : 0.f;
        }
    }
}

// ---------------- GRU gate combine ----------------

__global__ void k_gru(const float* __restrict__ gi, const float* __restrict__ gh,
                      const float* __restrict__ bih, const float* __restrict__ bhh,
                      float* __restrict__ hgru) {
    int idx = blockIdx.x * 256 + threadIdx.x;
    if (idx >= N_NODES * CDIM) return;
    int n = idx >> 6, c = idx & 63;
    const float* gin = gi + (size_t)n * G3;
    const float* ghn = gh + (size_t)n * G3;
    float ir = gin[c] + bih[c];
    float iz = gin[64 + c] + bih[64 + c];
    float ig = gin[128 + c] + bih[128 + c];
    float hr = ghn[c] + bhh[c];
    float hz = ghn[64 + c] + bhh[64 + c];
    float hg = ghn[128 + c] + bhh[128 + c];
    float r = 1.f / (1.f + expf(-(ir + hr)));
    float z = 1.f / (1.f + expf(-(iz + hz)));
    float g = tanhf(ig + r * hg);
    float hp = hgru[idx];
    hgru[idx] = (1.f - z) * g + z * hp;
}

// ---------------- final linear ----------------

__global__ void k_out(const float* __restrict__ hg, const float* __restrict__ Wout,
                      const float* __restrict__ bout, float* __restrict__ out) {
    int n = blockIdx.x * 256 + threadIdx.x;
    if (n >= N_NODES) return;
    float s = 0.f;
    for (int c = 0; c < CDIM; ++c) s = fmaf(hg[(size_t)n * CDIM + c], Wout[c], s);
    out[n] = s + bout[0];
}

// ---------------- launch ----------------

extern "C" void kernel_launch(void* const* d_in, const int* in_sizes, int n_in,
                              void* d_out, int out_size, void* d_ws, size_t ws_size,
                              hipStream_t stream) {
    const float* x   = (const float*)d_in[0];
    const int*   ei  = (const int*)d_in[1];
    const float* W1  = (const float*)d_in[2];
    const float* as1 = (const float*)d_in[3];
    const float* ad1 = (const float*)d_in[4];
    const float* b1  = (const float*)d_in[5];
    const float* W2  = (const float*)d_in[6];
    const float* as2 = (const float*)d_in[7];
    const float* ad2 = (const float*)d_in[8];
    const float* b2  = (const float*)d_in[9];
    const float* Wih = (const float*)d_in[10];
    const float* Whh = (const float*)d_in[11];
    const float* bih = (const float*)d_in[12];
    const float* bhh = (const float*)d_in[13];
    const float* Wout = (const float*)d_in[14];
    const float* bout = (const float*)d_in[15];

    float* ws = (float*)d_ws;
    float* h1   = ws; ws += (size_t)N_NODES * HC;     // gat1 / gat2 pre-agg features
    float* g1   = ws; ws += (size_t)N_NODES * HC;     // gat1 output
    float* g2   = ws; ws += (size_t)N_NODES * CDIM;   // gat2 output
    float* gi   = ws; ws += (size_t)N_NODES * G3;
    float* gh   = ws; ws += (size_t)N_NODES * G3;
    float* hgru = ws; ws += (size_t)N_NODES * CDIM;
    float* asb  = ws; ws += (size_t)N_NODES * HEADS;
    float* adb  = ws; ws += (size_t)N_NODES * HEADS;
    int* cnt = (int*)ws;
    int* cur = cnt + N_NODES;
    int* off = cur + N_NODES;
    int* csr = off + (N_NODES + 4);

    hipMemsetAsync(hgru, 0, (size_t)N_NODES * CDIM * sizeof(float), stream);

    dim3 thr(256);
    const int RB = (N_NODES + 63) / 64;   // 313 row tiles

    for (int t = 0; t < T_STEPS; ++t) {
        const int* ei_t = ei + (size_t)t * 2 * N_EDGES;

        k_init_cnt<<<(N_NODES + 255) / 256, thr, 0, stream>>>(cnt);
        k_count<<<(N_EDGES + 255) / 256, thr, 0, stream>>>(ei_t, cnt);
        k_scan<<<1, 1024, 0, stream>>>(cnt, off, cur);
        k_fill<<<(N_EDGES + N_NODES + 255) / 256, thr, 0, stream>>>(ei_t, cur, csr);

        // GAT layer 1
        k_gemm<<<dim3(HC / 64, RB), thr, 0, stream>>>(x + (size_t)t * F_INDIM, T_STEPS * F_INDIM,
                                                      W1, HC, h1, HC, N_NODES, F_INDIM);
        k_attn_prep<<<(N_NODES * HEADS + 255) / 256, thr, 0, stream>>>(h1, as1, ad1, asb, adb);
        k_gat_agg<true><<<N_NODES, thr, 0, stream>>>(h1, asb, adb, off, csr, b1, g1);

        // GAT layer 2
        k_gemm<<<dim3(HC / 64, RB), thr, 0, stream>>>(g1, HC, W2, HC, h1, HC, N_NODES, HC);
        k_attn_prep<<<(N_NODES * HEADS + 255) / 256, thr, 0, stream>>>(h1, as2, ad2, asb, adb);
        k_gat_agg<false><<<N_NODES, thr, 0, stream>>>(h1, asb, adb, off, csr, b2, g2);

        // GRU step
        k_gemm<<<dim3(G3 / 64, RB), thr, 0, stream>>>(g2, CDIM, Wih, G3, gi, G3, N_NODES, CDIM);
        k_gemm<<<dim3(G3 / 64, RB), thr, 0, stream>>>(hgru, CDIM, Whh, G3, gh, G3, N_NODES, CDIM);
        k_gru<<<(N_NODES * CDIM + 255) / 256, thr, 0, stream>>>(gi, gh, bih, bhh, hgru);
    }

    k_out<<<(N_NODES + 255) / 256, thr, 0, stream>>>(hgru, Wout, bout, (float*)d_out);
}

// Round 2
// 4218.945 us; speedup vs baseline: 1.1796x; 1.1796x over previous
//
#include <hip/hip_runtime.h>
#include <math.h>

#define N_NODES 20000
#define N_EDGES 320000
#define T_STEPS 16
#define TB 8                       // timesteps per half-batch
#define RB_ROWS (N_NODES * TB)     // 160000 rows, = 1250 * 128 exactly
#define F_INDIM 128
#define HC 256
#define HEADS 4
#define CDIM 64
#define G3 192
#define EPN (N_EDGES + N_NODES)    // 340000 edges incl self-loops per t

// ---------------- CSR build (all 16 timesteps in 4 launches) ----------------

__global__ void k_csr_init(int* __restrict__ cnt) {
    int i = blockIdx.x * 256 + threadIdx.x;
    if (i < T_STEPS * N_NODES) cnt[i] = 1;   // self-loop
}

__global__ void k_csr_count(const int* __restrict__ ei, int* __restrict__ cnt_all) {
    int t = blockIdx.y;
    int i = blockIdx.x * 256 + threadIdx.x;
    if (i < N_EDGES)
        atomicAdd(&cnt_all[t * N_NODES + ei[(size_t)t * 2 * N_EDGES + N_EDGES + i]], 1);
}

__global__ __launch_bounds__(1024) void k_csr_scan(const int* __restrict__ cnt_all,
                                                   int* __restrict__ off_all,
                                                   int* __restrict__ cur_all) {
    __shared__ int sdata[1024];
    const int t = blockIdx.x;
    const int* cnt = cnt_all + t * N_NODES;
    int* off = off_all + t * (N_NODES + 1);
    int* cur = cur_all + t * N_NODES;
    int tid = threadIdx.x;
    const int ITEMS = (N_NODES + 1023) / 1024;   // 20
    int start = tid * ITEMS;
    int local = 0;
    for (int i = 0; i < ITEMS; ++i) {
        int idx = start + i;
        if (idx < N_NODES) local += cnt[idx];
    }
    sdata[tid] = local;
    __syncthreads();
    for (int s = 1; s < 1024; s <<= 1) {
        int v = (tid >= s) ? sdata[tid - s] : 0;
        __syncthreads();
        sdata[tid] += v;
        __syncthreads();
    }
    int run = sdata[tid] - local;   // exclusive
    for (int i = 0; i < ITEMS; ++i) {
        int idx = start + i;
        if (idx < N_NODES) {
            off[idx] = run;
            cur[idx] = run;
            run += cnt[idx];
        }
    }
    if (tid == 0) off[N_NODES] = EPN;
}

__global__ void k_csr_fill(const int* __restrict__ ei, int* __restrict__ cur_all,
                           int* __restrict__ csr_all) {
    int t = blockIdx.y;
    int i = blockIdx.x * 256 + threadIdx.x;
    int* cur = cur_all + t * N_NODES;
    int* csr = csr_all + (size_t)t * EPN;
    const int* e = ei + (size_t)t * 2 * N_EDGES;
    if (i < N_EDGES) {
        int s = e[i], d = e[N_EDGES + i];
        csr[atomicAdd(&cur[d], 1)] = s;
    } else if (i < EPN) {
        int d = i - N_EDGES;
        csr[atomicAdd(&cur[d], 1)] = d;
    }
}

// ---------------- GEMM: C[RB_ROWS x 256] = A[RB_ROWS x K] * B[K x 256] ----------------
// 128x128 tile, 256 threads, 8x8 per thread (2x2 quads), BK=16.
// XMAP: A row l maps to x_sequence row (l/8)*16 + tbase + (l%8), lda = 128.

template <bool XMAP>
__global__ __launch_bounds__(256) void k_gemm(const float* __restrict__ A, int lda,
                                              const float* __restrict__ B, int ldb,
                                              float* __restrict__ C, int ldc,
                                              int K, int tbase) {
    __shared__ __align__(16) float As[16][132];
    __shared__ __align__(16) float Bs[16][128];
    const int tid = threadIdx.x;
    const int row0 = blockIdx.y * 128;
    const int col0 = blockIdx.x * 128;
    const int tx = tid & 15, ty = tid >> 4;
    float acc[8][8] = {};

    const int arow = tid >> 2;        // 0..63
    const int akq  = tid & 3;         // float4 index along k
    const int bcol = (tid & 31) * 4;
    const int bk   = tid >> 5;        // 0..7

    for (int kk = 0; kk < K; kk += 16) {
#pragma unroll
        for (int p = 0; p < 2; ++p) {
            int l = row0 + arow + 64 * p;
            int rg = XMAP ? (((l >> 3) << 4) + tbase + (l & 7)) : l;
            const float4 v = *(const float4*)&A[(size_t)rg * lda + kk + akq * 4];
            As[akq * 4 + 0][arow + 64 * p] = v.x;
            As[akq * 4 + 1][arow + 64 * p] = v.y;
            As[akq * 4 + 2][arow + 64 * p] = v.z;
            As[akq * 4 + 3][arow + 64 * p] = v.w;
        }
#pragma unroll
        for (int p = 0; p < 2; ++p) {
            int k = bk + 8 * p;
            *(float4*)&Bs[k][bcol] = *(const float4*)&B[(size_t)(kk + k) * ldb + col0 + bcol];
        }
        __syncthreads();
#pragma unroll
        for (int k = 0; k < 16; ++k) {
            float4 a0 = *(const float4*)&As[k][ty * 4];
            float4 a1 = *(const float4*)&As[k][64 + ty * 4];
            float4 b0 = *(const float4*)&Bs[k][tx * 4];
            float4 b1 = *(const float4*)&Bs[k][64 + tx * 4];
            float av[8] = {a0.x, a0.y, a0.z, a0.w, a1.x, a1.y, a1.z, a1.w};
            float bv[8] = {b0.x, b0.y, b0.z, b0.w, b1.x, b1.y, b1.z, b1.w};
#pragma unroll
            for (int i = 0; i < 8; ++i)
#pragma unroll
                for (int j = 0; j < 8; ++j)
                    acc[i][j] = fmaf(av[i], bv[j], acc[i][j]);
        }
        __syncthreads();
    }
#pragma unroll
    for (int ih = 0; ih < 2; ++ih)
#pragma unroll
        for (int i = 0; i < 4; ++i) {
            int row = row0 + ih * 64 + ty * 4 + i;
#pragma unroll
            for (int jh = 0; jh < 2; ++jh) {
                float4 v = make_float4(acc[ih * 4 + i][jh * 4 + 0], acc[ih * 4 + i][jh * 4 + 1],
                                       acc[ih * 4 + i][jh * 4 + 2], acc[ih * 4 + i][jh * 4 + 3]);
                *(float4*)&C[(size_t)row * ldc + col0 + jh * 64 + tx * 4] = v;
            }
        }
}

// ---------------- attention alpha prep over the whole half-batch ----------------

__global__ void k_attn_prep(const float* __restrict__ h, const float* __restrict__ a_src,
                            const float* __restrict__ a_dst,
                            float* __restrict__ asb, float* __restrict__ adb) {
    int idx = blockIdx.x * 256 + threadIdx.x;
    if (idx >= RB_ROWS * HEADS) return;
    int r = idx >> 2, hh = idx & 3;
    const float4* row = (const float4*)(h + (size_t)r * HC + hh * CDIM);
    const float4* av = (const float4*)(a_src + hh * CDIM);
    const float4* bv = (const float4*)(a_dst + hh * CDIM);
    float s1 = 0.f, s2 = 0.f;
#pragma unroll
    for (int c4 = 0; c4 < CDIM / 4; ++c4) {
        float4 v = row[c4], a = av[c4], b = bv[c4];
        s1 += v.x * a.x + v.y * a.y + v.z * a.z + v.w * a.w;
        s2 += v.x * b.x + v.y * b.y + v.z * b.z + v.w * b.w;
    }
    asb[idx] = s1;
    adb[idx] = s2;
}

// ---------------- GAT aggregation: grid (N_NODES, TB) ----------------
// feature rows in half-batch layout: row(s, tl) = s*TB + tl

template <bool CONCAT>
__global__ __launch_bounds__(256) void k_gat_agg(const float* __restrict__ hfeat,
                                                 const float* __restrict__ asb,
                                                 const float* __restrict__ adb,
                                                 const int* __restrict__ off_all,
                                                 const int* __restrict__ csr_all,
                                                 const float* __restrict__ bias,
                                                 float* __restrict__ out, int tbase) {
    __shared__ float s_max[HEADS];
    __shared__ int s_src[64];
    __shared__ float s_w[64][HEADS];
    __shared__ float s_acc[HEADS][CDIM];

    const int tl = blockIdx.y;
    const int t = tbase + tl;
    const int d = blockIdx.x;
    const int tid = threadIdx.x;
    const int h = tid >> 6;       // wave = head
    const int c = tid & 63;       // lane = channel
    const int* off = off_all + (size_t)t * (N_NODES + 1);
    const int* csr = csr_all + (size_t)t * EPN;
    const int beg = off[d];
    const int deg = off[d + 1] - beg;

    // phase 1: per-head max of leaky_relu(as[src]+ad[d])
    float adh = adb[((size_t)d * TB + tl) * HEADS + h];
    float lmax = -1e30f;
    for (int j = c; j < deg; j += 64) {
        int s = csr[beg + j];
        float sc = asb[((size_t)s * TB + tl) * HEADS + h] + adh;
        sc = sc > 0.f ? sc : 0.2f * sc;
        lmax = fmaxf(lmax, sc);
    }
#pragma unroll
    for (int sh = 32; sh >= 1; sh >>= 1)
        lmax = fmaxf(lmax, __shfl_xor(lmax, sh, 64));
    if (c == 0) s_max[h] = lmax;
    __syncthreads();

    const int hhw = tid & 3;
    const float mC = s_max[hhw];
    const float adC = adb[((size_t)d * TB + tl) * HEADS + hhw];

    float acc = 0.f, denom = 0.f;
    for (int base = 0; base < deg; base += 64) {
        int len = min(64, deg - base);
        __syncthreads();
        if (tid < 64) s_src[tid] = (tid < len) ? csr[beg + base + tid] : 0;
        __syncthreads();
        {
            int j = tid >> 2;
            float w = 0.f;
            if (j < len) {
                int s = s_src[j];
                float sc = asb[((size_t)s * TB + tl) * HEADS + hhw] + adC;
                sc = sc > 0.f ? sc : 0.2f * sc;
                w = expf(sc - mC);
            }
            s_w[j][hhw] = w;
        }
        __syncthreads();
        for (int j = 0; j < len; ++j) {
            float w = s_w[j][h];
            denom += w;
            acc = fmaf(w, hfeat[((size_t)s_src[j] * TB + tl) * HC + h * CDIM + c], acc);
        }
    }
    float val = acc / (denom + 1e-16f);

    if (CONCAT) {
        float o = val + bias[h * CDIM + c];
        out[((size_t)d * TB + tl) * HC + h * CDIM + c] = fmaxf(o, 0.f);
    } else {
        s_acc[h][c] = val;
        __syncthreads();
        if (tid < CDIM) {
            float m = (s_acc[0][tid] + s_acc[1][tid] + s_acc[2][tid] + s_acc[3][tid]) * 0.25f;
            float o = m + bias[tid];
            out[((size_t)d * T_STEPS + t) * CDIM + tid] = fmaxf(o, 0.f);
        }
    }
}

// ---------------- fused GRU step: both GEMVs + gates, in-place hgru ----------------
// 1250 blocks x 192 threads, 16 nodes/block. g2_all layout: row(n,t) = n*T_STEPS + t.

__global__ __launch_bounds__(192) void k_gru(const float* __restrict__ g2_all,
                                             const float* __restrict__ Wih,
                                             const float* __restrict__ Whh,
                                             const float* __restrict__ bih,
                                             const float* __restrict__ bhh,
                                             float* __restrict__ hgru, int t) {
    __shared__ float sA[16][64], sH[16][64];
    __shared__ float sGI[16][192], sGH[16][192];
    const int tid = threadIdx.x;
    const int node0 = blockIdx.x * 16;
    for (int idx = tid; idx < 16 * 64; idx += 192) {
        int n = idx >> 6, c = idx & 63;
        sA[n][c] = g2_all[((size_t)(node0 + n) * T_STEPS + t) * CDIM + c];
        sH[n][c] = hgru[(size_t)(node0 + n) * CDIM + c];
    }
    __syncthreads();
    float accI[16] = {}, accH[16] = {};
#pragma unroll 4
    for (int k = 0; k < 64; ++k) {
        float wi = Wih[k * G3 + tid];
        float wh = Whh[k * G3 + tid];
#pragma unroll
        for (int n = 0; n < 16; ++n) {
            accI[n] = fmaf(sA[n][k], wi, accI[n]);
            accH[n] = fmaf(sH[n][k], wh, accH[n]);
        }
    }
#pragma unroll
    for (int n = 0; n < 16; ++n) {
        sGI[n][tid] = accI[n];
        sGH[n][tid] = accH[n];
    }
    __syncthreads();
    for (int idx = tid; idx < 16 * 64; idx += 192) {
        int n = idx >> 6, c = idx & 63;
        float ir = sGI[n][c] + bih[c];
        float iz = sGI[n][64 + c] + bih[64 + c];
        float ig = sGI[n][128 + c] + bih[128 + c];
        float hr = sGH[n][c] + bhh[c];
        float hz = sGH[n][64 + c] + bhh[64 + c];
        float hg = sGH[n][128 + c] + bhh[128 + c];
        float r = 1.f / (1.f + expf(-(ir + hr)));
        float z = 1.f / (1.f + expf(-(iz + hz)));
        float g = tanhf(ig + r * hg);
        float hp = sH[n][c];
        hgru[(size_t)(node0 + n) * CDIM + c] = (1.f - z) * g + z * hp;
    }
}

// ---------------- final linear ----------------

__global__ void k_out(const float* __restrict__ hg, const float* __restrict__ Wout,
                      const float* __restrict__ bout, float* __restrict__ out) {
    int n = blockIdx.x * 256 + threadIdx.x;
    if (n >= N_NODES) return;
    const float4* row = (const float4*)(hg + (size_t)n * CDIM);
    const float4* w = (const float4*)Wout;
    float s = 0.f;
#pragma unroll
    for (int i = 0; i < CDIM / 4; ++i) {
        float4 a = row[i], b = w[i];
        s += a.x * b.x + a.y * b.y + a.z * b.z + a.w * b.w;
    }
    out[n] = s + bout[0];
}

// ---------------- launch ----------------

extern "C" void kernel_launch(void* const* d_in, const int* in_sizes, int n_in,
                              void* d_out, int out_size, void* d_ws, size_t ws_size,
                              hipStream_t stream) {
    const float* x   = (const float*)d_in[0];
    const int*   ei  = (const int*)d_in[1];
    const float* W1  = (const float*)d_in[2];
    const float* as1 = (const float*)d_in[3];
    const float* ad1 = (const float*)d_in[4];
    const float* b1  = (const float*)d_in[5];
    const float* W2  = (const float*)d_in[6];
    const float* as2 = (const float*)d_in[7];
    const float* ad2 = (const float*)d_in[8];
    const float* b2  = (const float*)d_in[9];
    const float* Wih = (const float*)d_in[10];
    const float* Whh = (const float*)d_in[11];
    const float* bih = (const float*)d_in[12];
    const float* bhh = (const float*)d_in[13];
    const float* Wout = (const float*)d_in[14];
    const float* bout = (const float*)d_in[15];

    float* ws = (float*)d_ws;
    float* h_half  = ws; ws += (size_t)RB_ROWS * HC;             // 163.8 MB
    float* g1_half = ws; ws += (size_t)RB_ROWS * HC;             // 163.8 MB
    float* g2_all  = ws; ws += (size_t)N_NODES * T_STEPS * CDIM; // 81.9 MB
    float* hgru    = ws; ws += (size_t)N_NODES * CDIM;           // 5.1 MB
    float* asb     = ws; ws += (size_t)RB_ROWS * HEADS;          // 2.56 MB
    float* adb     = ws; ws += (size_t)RB_ROWS * HEADS;          // 2.56 MB
    int* cnt_all = (int*)ws;
    int* cur_all = cnt_all + T_STEPS * N_NODES;
    int* off_all = cur_all + T_STEPS * N_NODES;
    int* csr_all = off_all + T_STEPS * (N_NODES + 1);
    // total ~445 MB of the ~655 MB workspace

    hipMemsetAsync(hgru, 0, (size_t)N_NODES * CDIM * sizeof(float), stream);

    dim3 thr(256);

    // CSR for all timesteps
    k_csr_init<<<(T_STEPS * N_NODES + 255) / 256, thr, 0, stream>>>(cnt_all);
    k_csr_count<<<dim3((N_EDGES + 255) / 256, T_STEPS), thr, 0, stream>>>(ei, cnt_all);
    k_csr_scan<<<T_STEPS, 1024, 0, stream>>>(cnt_all, off_all, cur_all);
    k_csr_fill<<<dim3((EPN + 255) / 256, T_STEPS), thr, 0, stream>>>(ei, cur_all, csr_all);

    for (int hb = 0; hb < 2; ++hb) {
        const int tbase = hb * TB;
        // GAT layer 1 over 8 timesteps at once
        k_gemm<true><<<dim3(2, RB_ROWS / 128), thr, 0, stream>>>(x, F_INDIM, W1, HC,
                                                                 h_half, HC, F_INDIM, tbase);
        k_attn_prep<<<(RB_ROWS * HEADS + 255) / 256, thr, 0, stream>>>(h_half, as1, ad1, asb, adb);
        k_gat_agg<true><<<dim3(N_NODES, TB), thr, 0, stream>>>(h_half, asb, adb, off_all, csr_all,
                                                               b1, g1_half, tbase);
        // GAT layer 2 (h_half reused as the pre-agg buffer)
        k_gemm<false><<<dim3(2, RB_ROWS / 128), thr, 0, stream>>>(g1_half, HC, W2, HC,
                                                                  h_half, HC, HC, tbase);
        k_attn_prep<<<(RB_ROWS * HEADS + 255) / 256, thr, 0, stream>>>(h_half, as2, ad2, asb, adb);
        k_gat_agg<false><<<dim3(N_NODES, TB), thr, 0, stream>>>(h_half, asb, adb, off_all, csr_all,
                                                                b2, g2_all, tbase);
    }

    for (int t = 0; t < T_STEPS; ++t)
        k_gru<<<RB_ROWS / 128, 192, 0, stream>>>(g2_all, Wih, Whh, bih, bhh, hgru, t);

    k_out<<<(N_NODES + 255) / 256, thr, 0, stream>>>(hgru, Wout, bout, (float*)d_out);
}